// Round 8
// baseline (235.630 us; speedup 1.0000x reference)
//
#include <hip/hip_runtime.h>
#include <hip/hip_bf16.h>

// SNN IF scan, T=4. Memory-bound: 134 MB in + 134 MB out. History:
//   plain loads, batch collapsed (R0/R2/R5/R7, VGPR<=72): ~80-82 us, 3.3 TB/s
//   nt loads, batch survived   (R4 16-deep, R6 32-deep):  ~70/67 us, 4.0 TB/s
// R8 isolates nt-vs-plain WITH batching held: plain loads + a hard
// asm-volatile "memory" fence after the batch (sched_barrier(0) alone
// provably failed to pin plain loads in R7 — VGPR fell to 72). Plain loads
// matter because harness restore leaves ~half of x LLC-resident (FETCH=65 MB
// in every plain round): if the 4 TB/s service rate holds, HBM only moves
// 201 MB -> ~55-60 us. VGPR_Count >= ~140 is the validity check.
// Stores stay nt (output never re-read; don't evict x from LLC).

#define T_STEPS 4
#define UNROLL 8

typedef float vfloat4 __attribute__((ext_vector_type(4)));

__global__ __launch_bounds__(256) void IF_18622978195596_kernel(
    const vfloat4* __restrict__ x, const float* __restrict__ thresh_p,
    vfloat4* __restrict__ out, int n4) {
    // n4 = 2^21 divides exactly by 256*UNROLL = 2048; no guards.
    const int base = blockIdx.x * (256 * UNROLL) + threadIdx.x;
    const float th = *thresh_p;

    // ---- load phase: 32 independent cached loads, issued in consume order ----
    vfloat4 xv[UNROLL][T_STEPS];
#pragma unroll
    for (int u = 0; u < UNROLL; ++u) {
        const int i = base + u * 256;
#pragma unroll
        for (int t = 0; t < T_STEPS; ++t) {
            xv[u][t] = x[(size_t)t * n4 + i];
        }
    }
    // Hard pin: possibly-memory-writing fence — no load may sink below this,
    // at IR or MIR level; all 32 values must be live here.
    asm volatile("" ::: "memory");
    __builtin_amdgcn_sched_barrier(0);

    // ---- consume phase, in issue order -> progressive vmcnt drain ----
#pragma unroll
    for (int u = 0; u < UNROLL; ++u) {
        const int i = base + u * 256;
        vfloat4 mem = {0.5f * th, 0.5f * th, 0.5f * th, 0.5f * th};
#pragma unroll
        for (int t = 0; t < T_STEPS; ++t) {
            mem += xv[u][t];
            vfloat4 s;
            s.x = (mem.x >= th) ? th : 0.0f;
            s.y = (mem.y >= th) ? th : 0.0f;
            s.z = (mem.z >= th) ? th : 0.0f;
            s.w = (mem.w >= th) ? th : 0.0f;
            mem -= s;
            __builtin_nontemporal_store(s, &out[(size_t)t * n4 + i]);
        }
    }
}

extern "C" void kernel_launch(void* const* d_in, const int* in_sizes, int n_in,
                              void* d_out, int out_size, void* d_ws, size_t ws_size,
                              hipStream_t stream) {
    const float* x = (const float*)d_in[0];
    const float* thresh = (const float*)d_in[1];
    float* out = (float*)d_out;

    int total = in_sizes[0];              // 33,554,432 floats
    int n_per_t = total / T_STEPS;        // 8,388,608 neurons
    int n4 = n_per_t / 4;                 // 2,097,152 vfloat4 per timestep

    int block = 256;
    int per_block = block * UNROLL;       // 2048 vfloat4 per block per t
    int grid = n4 / per_block;            // 1024 blocks = 4 per CU, exact
    IF_18622978195596_kernel<<<grid, block, 0, stream>>>(
        (const vfloat4*)x, thresh, (vfloat4*)out, n4);
}

// Round 9
// 223.004 us; speedup vs baseline: 1.0566x; 1.0566x over previous
//
#include <hip/hip_runtime.h>
#include <hip/hip_bf16.h>

// SNN IF scan, T=4. Memory-bound: 134 MB in + 134 MB out. History:
//   plain loads (any structure, R0/R2/R5/R7/R8): ~81-82 us
//   nt loads    (R4 t-major 16-deep, R6 u-major 32-deep): ~70 / ~67 us
// R8 insight: the asm fence can't pin the batch — scalar consume arithmetic
// hoists ABOVE the fence (it's not a memory op), so register batching was
// never cleanly held; load cache policy (nt vs plain) explains the two
// speed classes, not batch depth.
// R9 isolates the STORE policy (never tested alone): exact R6 structure,
// nt loads kept, stores switched nt -> PLAIN. fillBuffer sustains
// 6.6-6.9 TB/s through the plain write path; if nt-store bypass was capping
// writes (~3 TB/s would give 21+44=65 us, matching R6's 67), plain stores
// should land ~55-62 us. nt loads bypass LLC, so store allocation can't
// confound read hits — single clean variable.

#define T_STEPS 4
#define UNROLL 8

typedef float vfloat4 __attribute__((ext_vector_type(4)));

__global__ __launch_bounds__(256) void IF_18622978195596_kernel(
    const vfloat4* __restrict__ x, const float* __restrict__ thresh_p,
    vfloat4* __restrict__ out, int n4) {
    // n4 = 2^21 divides exactly by 256*UNROLL = 2048; no guards.
    const int base = blockIdx.x * (256 * UNROLL) + threadIdx.x;
    const float th = *thresh_p;

    // ---- load phase: 32 independent nt loads, issued in consume order ----
    vfloat4 xv[UNROLL][T_STEPS];
#pragma unroll
    for (int u = 0; u < UNROLL; ++u) {
        const int i = base + u * 256;
#pragma unroll
        for (int t = 0; t < T_STEPS; ++t) {
            xv[u][t] = __builtin_nontemporal_load(&x[(size_t)t * n4 + i]);
        }
    }
    __builtin_amdgcn_sched_barrier(0);

    // ---- consume phase, in issue order -> progressive vmcnt drain ----
#pragma unroll
    for (int u = 0; u < UNROLL; ++u) {
        const int i = base + u * 256;
        vfloat4 mem = {0.5f * th, 0.5f * th, 0.5f * th, 0.5f * th};
#pragma unroll
        for (int t = 0; t < T_STEPS; ++t) {
            mem += xv[u][t];
            vfloat4 s;
            s.x = (mem.x >= th) ? th : 0.0f;
            s.y = (mem.y >= th) ? th : 0.0f;
            s.z = (mem.z >= th) ? th : 0.0f;
            s.w = (mem.w >= th) ? th : 0.0f;
            mem -= s;
            out[(size_t)t * n4 + i] = s;   // PLAIN store (R9's single change)
        }
    }
}

extern "C" void kernel_launch(void* const* d_in, const int* in_sizes, int n_in,
                              void* d_out, int out_size, void* d_ws, size_t ws_size,
                              hipStream_t stream) {
    const float* x = (const float*)d_in[0];
    const float* thresh = (const float*)d_in[1];
    float* out = (float*)d_out;

    int total = in_sizes[0];              // 33,554,432 floats
    int n_per_t = total / T_STEPS;        // 8,388,608 neurons
    int n4 = n_per_t / 4;                 // 2,097,152 vfloat4 per timestep

    int block = 256;
    int per_block = block * UNROLL;       // 2048 vfloat4 per block per t
    int grid = n4 / per_block;            // 1024 blocks = 4 per CU, exact
    IF_18622978195596_kernel<<<grid, block, 0, stream>>>(
        (const vfloat4*)x, thresh, (vfloat4*)out, n4);
}